// Round 16
// baseline (422.989 us; speedup 1.0000x reference)
//
#include <hip/hip_runtime.h>

#define S_  512
#define B_  256
#define NIN 180

typedef float v2 __attribute__((ext_vector_type(2)));

#define SSIG  -1.4426950408889634f
#define STANH -2.8853900817779268f

// ---- DPP ctrl encodings (verified on HW r5-r15) ----
#define QP_X1 0xB1
#define QP_X2 0x4E
#define QP_X3 0x1B
#define ROR4  0x124
#define ROR8  0x128

template<int CTRL>
__device__ __forceinline__ float dppf(float x) {
    return __uint_as_float((unsigned)__builtin_amdgcn_update_dpp(
        0, (int)__float_as_uint(x), CTRL, 0xF, 0xF, true));
}

#define ROTS8(h, r) do { \
    r[0] = (h); \
    r[1] = dppf<QP_X1>(h); \
    r[2] = dppf<QP_X2>(h); \
    r[3] = dppf<QP_X3>(h); \
    r[4] = dppf<ROR4>(h); \
    r[5] = dppf<QP_X1>(r[4]); \
    r[6] = dppf<QP_X2>(r[4]); \
    r[7] = dppf<QP_X3>(r[4]); \
} while (0)

// ONE kernel: 64 blocks x 512 thr (8 waves).
// Waves 0-3: verified scan (A1 layer0, A2 a1p, B layer1, W3 proj).
// Waves 4-7: xg producers for THIS block's 4 chains only (no cross-block
// traffic). Handoff via 16-slot LDS ring3, barrier-separated (timing-safe).
// Barrier ledger: every wave executes exactly 133 __syncthreads:
// P0 (wpk) + P1,P2 (rows 0-7) + 128 phase barriers + 2 tail.
__global__ __launch_bounds__(512, 1) void lstm_all(
    const float* __restrict__ x,
    const float* __restrict__ w_ih0, const float* __restrict__ b_ih0,
    const float* __restrict__ b_hh0, const float* __restrict__ w_hh0,
    const float* __restrict__ w_ih1, const float* __restrict__ w_hh1,
    const float* __restrict__ b_ih1, const float* __restrict__ b_hh1,
    const float* __restrict__ w_reg, const float* __restrict__ b_reg,
    float* __restrict__ out)
{
    __shared__ float ring0[16][64];     // h0(u) at slot u&15
    __shared__ float ring1[16][128];    // a1p(u) (v2) at slot u&15
    __shared__ float ring2[16][64];     // h1(u) at slot u&15
    __shared__ float ring3[16][128];    // xg slice (v2) at slot u&15
    __shared__ v2    wpk[16][182];      // {w_ih0[p], w_ih0[p+16]} pairs
    __shared__ float xrow[4][2][4][184];// per-producer-wave x staging

    const int tid = threadIdx.x;
    const int wid = tid >> 6;          // 0=A1 1=A2 2=B 3=proj 4..7=producers
    const int lt  = tid & 63;
    const int j   = lt & 7;
    const int b3  = (lt >> 3) & 1;
    const int cc  = lt >> 4;
    const bool b3z = (b3 == 0);
    const int bid = blockIdx.x;        // 0..63

    const int gA = b3 * 8 + j;
    const int gB = (2 + b3) * 8 + j;
    const float sB_ = b3z ? STANH : SSIG;
    const float aB  = b3z ? 2.0f : 1.0f;
    const float bB  = b3z ? -1.0f : 0.0f;

    auto COMBINE2 = [&](float tA, float tB, float& c, float& h) {
        float m  = tA * tB;
        float mr = dppf<ROR8>(m);
        float fa = dppf<ROR8>(tA);
        float ob = dppf<ROR8>(tB);
        float ig = b3z ? m  : mr;
        float f  = b3z ? fa : tA;
        float o  = b3z ? ob : tB;
        c = __builtin_fmaf(f, c, ig);
        float th = __builtin_fmaf(2.0f, __builtin_amdgcn_rcpf(
            1.0f + __builtin_amdgcn_exp2f(STANH * c)), -1.0f);
        h = o * th;
    };

    // ---- common prelude: stage packed layer-0 input weights ----
    for (int idx = tid; idx < 2880; idx += 512) {
        int p = idx / 180, i = idx - p * 180;
        wpk[p][i] = v2{w_ih0[p * 180 + i], w_ih0[(p + 16) * 180 + i]};
    }
    __syncthreads();                                      // P0

    if (wid == 0) {
        // ----- wave A1: layer-0 recurrence (xq from ring3) -----
        v2 w0p[8];
        #pragma unroll
        for (int m = 0; m < 8; ++m) {
            int k = j ^ m;
            w0p[m] = v2{SSIG * w_hh0[gA * 8 + k], sB_ * w_hh0[gB * 8 + k]};
        }
        float h0p = 0.f, c0v = 0.f;
        __syncthreads();                                  // P1
        __syncthreads();                                  // P2

        for (int ph = 0; ph < 128; ++ph) {
            const int sb = (ph & 3) * 4;
            v2 xq[4];
            #pragma unroll
            for (int k = 0; k < 4; ++k)
                xq[k] = *(const v2*)&ring3[sb + k][lt * 2];
            #pragma unroll
            for (int k = 0; k < 4; ++k) {
                float r0[8];
                ROTS8(h0p, r0);
                v2 a0L = __builtin_elementwise_fma(w0p[0], v2{r0[0], r0[0]}, xq[k]);
                v2 a0H = w0p[4] * v2{r0[4], r0[4]};
                #pragma unroll
                for (int m = 1; m < 4; ++m) {
                    a0L = __builtin_elementwise_fma(w0p[m], v2{r0[m], r0[m]}, a0L);
                    a0H = __builtin_elementwise_fma(w0p[m + 4], v2{r0[m + 4], r0[m + 4]}, a0H);
                }
                v2 a0 = a0L + a0H;
                float eA = __builtin_amdgcn_exp2f(a0.x);
                float eB = __builtin_amdgcn_exp2f(a0.y);
                float tA = __builtin_amdgcn_rcpf(1.0f + eA);
                float tB = __builtin_fmaf(aB, __builtin_amdgcn_rcpf(1.0f + eB), bB);
                COMBINE2(tA, tB, c0v, h0p);
                ring0[sb + k][lt] = h0p;
            }
            __syncthreads();                              // B0..B127
        }
        __syncthreads();                                  // T1
        __syncthreads();                                  // T2
    } else if (wid == 1) {
        // ----- wave A2: a1p = b1 + Wih1*h0 -----
        v2 wi1p[8];
        #pragma unroll
        for (int m = 0; m < 8; ++m) {
            int k = j ^ m;
            wi1p[m] = v2{SSIG * w_ih1[gA * 8 + k], sB_ * w_ih1[gB * 8 + k]};
        }
        const v2 b1p = v2{SSIG * (b_ih1[gA] + b_hh1[gA]),
                          sB_  * (b_ih1[gB] + b_hh1[gB])};
        __syncthreads();                                  // P1
        __syncthreads();                                  // P2

        __syncthreads();                                  // B0
        for (int p = 1; p <= 128; ++p) {
            const int sb = ((p - 1) & 3) * 4;
            float h0v[4];
            #pragma unroll
            for (int k = 0; k < 4; ++k) h0v[k] = ring0[sb + k][lt];
            #pragma unroll
            for (int k = 0; k < 4; ++k) {
                float r0[8];
                ROTS8(h0v[k], r0);
                v2 a = __builtin_elementwise_fma(wi1p[0], v2{r0[0], r0[0]}, b1p);
                #pragma unroll
                for (int m = 1; m < 8; ++m)
                    a = __builtin_elementwise_fma(wi1p[m], v2{r0[m], r0[m]}, a);
                *(v2*)&ring1[sb + k][lt * 2] = a;
            }
            __syncthreads();                              // B1..B127,T1
        }
        __syncthreads();                                  // T2
    } else if (wid == 2) {
        // ----- wave B: layer-1 recurrence -> ring2 -----
        v2 wh1p[8];
        #pragma unroll
        for (int m = 0; m < 8; ++m) {
            int k = j ^ m;
            wh1p[m] = v2{SSIG * w_hh1[gA * 8 + k], sB_ * w_hh1[gB * 8 + k]};
        }
        float h1p = 0.f, c1v = 0.f;

        auto BODY4 = [&](int p) {
            const int sb = ((p - 2) & 3) * 4;
            v2 a1in[4];
            #pragma unroll
            for (int k = 0; k < 4; ++k) a1in[k] = *(const v2*)&ring1[sb + k][lt * 2];
            #pragma unroll
            for (int k = 0; k < 4; ++k) {
                float r1[8];
                ROTS8(h1p, r1);
                v2 aL = __builtin_elementwise_fma(wh1p[0], v2{r1[0], r1[0]}, a1in[k]);
                v2 aH = wh1p[4] * v2{r1[4], r1[4]};
                #pragma unroll
                for (int m = 1; m < 4; ++m) {
                    aL = __builtin_elementwise_fma(wh1p[m], v2{r1[m], r1[m]}, aL);
                    aH = __builtin_elementwise_fma(wh1p[m + 4], v2{r1[m + 4], r1[m + 4]}, aH);
                }
                v2 a1 = aL + aH;
                float eA = __builtin_amdgcn_exp2f(a1.x);
                float eB = __builtin_amdgcn_exp2f(a1.y);
                float tA = __builtin_amdgcn_rcpf(1.0f + eA);
                float tB = __builtin_fmaf(aB, __builtin_amdgcn_rcpf(1.0f + eB), bB);
                COMBINE2(tA, tB, c1v, h1p);
                ring2[sb + k][lt] = h1p;
            }
        };

        __syncthreads();                                  // P1
        __syncthreads();                                  // P2
        __syncthreads();                                  // B0
        __syncthreads();                                  // B1
        for (int p = 2; p <= 128; ++p) { BODY4(p); __syncthreads(); } // B2..T1
        BODY4(129);                                       // steps 508..511
        __syncthreads();                                  // T2
    } else if (wid == 3) {
        // ----- wave W3: projection -----
        float wrl[8];
        #pragma unroll
        for (int m = 0; m < 8; ++m) wrl[m] = w_reg[b3 * 8 + (j ^ m)];
        const float br  = b_reg[b3];
        const bool isl  = (j == 0);
        const int  ooff = (bid * 4 + cc) * 2 + b3;

        auto PBODY = [&](int sb, int wbase) {
            float h1v[4];
            #pragma unroll
            for (int k = 0; k < 4; ++k) h1v[k] = ring2[sb + k][lt];
            #pragma unroll
            for (int k = 0; k < 4; ++k) {
                float r1[8];
                ROTS8(h1v[k], r1);
                float pp = br;
                #pragma unroll
                for (int m = 0; m < 8; ++m) pp = __builtin_fmaf(wrl[m], r1[m], pp);
                if (isl) out[(size_t)(wbase + k) * 512 + ooff] = pp;
            }
        };

        __syncthreads();                                  // P1
        __syncthreads();                                  // P2
        __syncthreads();                                  // B0
        __syncthreads();                                  // B1
        __syncthreads();                                  // B2
        for (int p = 3; p <= 129; ++p) {
            PBODY(((p - 3) & 3) * 4, 4 * (p - 3));
            __syncthreads();                              // B3..T2
        }
        PBODY(12, 508);                                   // steps 508..511
    } else {
        // ----- waves G0..G3: xg producers (rows u = 4*ph + 8 + gw) -----
        const int gw = wid - 4;
        const int bl = lt >> 4;            // chain-local batch row 0..3
        const int p  = lt & 15;            // gate-pair index
        const v2 sc = v2{SSIG, (p < 8) ? STANH : SSIG};
        const v2 bsc = sc * v2{b_ih0[p] + b_hh0[p],
                               b_ih0[p + 16] + b_hh0[p + 16]};

        auto XLOAD = [&](int r, float4* xr) {
            const float* src = x + ((size_t)r * B_ + 4 * bid) * NIN;
            #pragma unroll
            for (int k = 0; k < 3; ++k) {
                int f4 = lt + 64 * k;
                if (f4 < 180) xr[k] = *(const float4*)(src + 4 * f4);
            }
        };
        auto XSTORE = [&](int buf, const float4* xr) {
            #pragma unroll
            for (int k = 0; k < 3; ++k) {
                int f4 = lt + 64 * k;
                if (f4 < 180) {
                    int b = f4 / 45, c4 = (f4 - b * 45) * 4;
                    *(float4*)&xrow[gw][buf][b][c4] = xr[k];
                }
            }
        };
        auto PROW = [&](int r, int buf) {
            v2 acc = v2{0.f, 0.f};
            const float* xr_ = &xrow[gw][buf][bl][0];
            #pragma unroll 9
            for (int i4 = 0; i4 < 45; ++i4) {
                float4 xv = *(const float4*)(xr_ + 4 * i4);
                v2 w0 = wpk[p][4 * i4];
                v2 w1 = wpk[p][4 * i4 + 1];
                v2 w2 = wpk[p][4 * i4 + 2];
                v2 w3 = wpk[p][4 * i4 + 3];
                acc = __builtin_elementwise_fma(w0, v2{xv.x, xv.x}, acc);
                acc = __builtin_elementwise_fma(w1, v2{xv.y, xv.y}, acc);
                acc = __builtin_elementwise_fma(w2, v2{xv.z, xv.z}, acc);
                acc = __builtin_elementwise_fma(w3, v2{xv.w, xv.w}, acc);
            }
            v2 o = __builtin_elementwise_fma(acc, sc, bsc);
            *(v2*)&ring3[r & 15][lt * 2] = o;
        };

        float4 xa[3], xb[3];
        XLOAD(gw, xa);
        XLOAD(4 + gw, xb);
        XSTORE(0, xa);
        PROW(gw, 0);                      // rows 0..3
        __syncthreads();                  // P1
        XSTORE(1, xb);
        XLOAD(8 + gw, xa);
        PROW(4 + gw, 1);                  // rows 4..7
        __syncthreads();                  // P2
        for (int ph = 0; ph <= 125; ++ph) {
            const int buf = ph & 1;
            XSTORE(buf, xa);              // row 4*ph+8+gw
            if (ph < 125) XLOAD(4 * ph + 12 + gw, xa);
            PROW(4 * ph + 8 + gw, buf);
            __syncthreads();              // B0..B125
        }
        __syncthreads();                  // B126
        __syncthreads();                  // B127
        __syncthreads();                  // T1
        __syncthreads();                  // T2
    }
}

extern "C" void kernel_launch(void* const* d_in, const int* in_sizes, int n_in,
                              void* d_out, int out_size, void* d_ws, size_t ws_size,
                              hipStream_t stream) {
    (void)in_sizes; (void)n_in; (void)out_size; (void)d_ws; (void)ws_size;
    const float* x     = (const float*)d_in[0];
    const float* w_ih0 = (const float*)d_in[1];
    const float* w_hh0 = (const float*)d_in[2];
    const float* b_ih0 = (const float*)d_in[3];
    const float* b_hh0 = (const float*)d_in[4];
    const float* w_ih1 = (const float*)d_in[5];
    const float* w_hh1 = (const float*)d_in[6];
    const float* b_ih1 = (const float*)d_in[7];
    const float* b_hh1 = (const float*)d_in[8];
    const float* w_reg = (const float*)d_in[9];
    const float* b_reg = (const float*)d_in[10];
    float* out = (float*)d_out;

    lstm_all<<<64, 512, 0, stream>>>(x, w_ih0, b_ih0, b_hh0, w_hh0,
                                     w_ih1, w_hh1, b_ih1, b_hh1,
                                     w_reg, b_reg, out);
}

// Round 17
// 114.538 us; speedup vs baseline: 3.6930x; 3.6930x over previous
//
#include <hip/hip_runtime.h>

#define S_  512
#define B_  256
#define NIN 180

typedef float v2 __attribute__((ext_vector_type(2)));

#define SSIG  -1.4426950408889634f
#define STANH -2.8853900817779268f

// ---- DPP ctrl encodings (verified on HW r5-r16) ----
#define QP_X1 0xB1
#define QP_X2 0x4E
#define QP_X3 0x1B
#define ROR4  0x124
#define ROR8  0x128

template<int CTRL>
__device__ __forceinline__ float dppf(float x) {
    return __uint_as_float((unsigned)__builtin_amdgcn_update_dpp(
        0, (int)__float_as_uint(x), CTRL, 0xF, 0xF, true));
}

#define ROTS8(h, r) do { \
    r[0] = (h); \
    r[1] = dppf<QP_X1>(h); \
    r[2] = dppf<QP_X2>(h); \
    r[3] = dppf<QP_X3>(h); \
    r[4] = dppf<ROR4>(h); \
    r[5] = dppf<QP_X1>(r[4]); \
    r[6] = dppf<QP_X2>(r[4]); \
    r[7] = dppf<QP_X3>(r[4]); \
} while (0)

// ======================= Kernel A: input GEMM v5 =======================
// r15 structure; x path changed: UNPADDED flat xs (lane-row base 720 B,
// 16B-aligned) so each ii is ONE ds_read_b128 (45 LDS instr/thread vs 180).
// Lane = row; wave = (qb, j0-pair); weights wave-uniform -> s_load + SGPR FMA.
__global__ __launch_bounds__(512) void xg_gemm(
    const float* __restrict__ x, const float* __restrict__ w,
    const float* __restrict__ bi, const float* __restrict__ bh,
    float* __restrict__ xg2)
{
    __shared__ float xs[64 * 180];

    const int tid = threadIdx.x;
    const int s   = blockIdx.x >> 2;
    const int rq  = blockIdx.x & 3;
    const int b0  = rq * 64;

    // ---- stage: flat coalesced float4 copy (rows b0..b0+63 contiguous) ----
    const float* xsrc = x + ((size_t)s * B_ + b0) * NIN;
    #pragma unroll
    for (int k = 0; k < 6; ++k) {
        int f4 = tid + k * 512;             // float4 index in [0, 2880)
        if (f4 < 2880) {
            float4 v = *(const float4*)(xsrc + 4 * (size_t)f4);
            *(float4*)&xs[4 * f4] = v;
        }
    }
    __syncthreads();

    // ---- compute ----
    const int wv   = __builtin_amdgcn_readfirstlane(tid >> 6);  // 0..7
    const int qb   = wv & 1;
    const int j0   = (wv >> 1) * 2;
    const int lane = tid & 63;
    const int b    = b0 + lane;

    const int gA0 = qb * 8 + j0;
    const int gB0 = (2 + qb) * 8 + j0;
    const float* wA0 = w + (size_t)gA0 * NIN;
    const float* wA1 = wA0 + NIN;
    const float* wB0 = w + (size_t)gB0 * NIN;
    const float* wB1 = wB0 + NIN;
    const float* xrow_ = &xs[lane * NIN];

    float a0 = 0.f, a1 = 0.f, a2 = 0.f, a3 = 0.f;
    #pragma unroll 9
    for (int ii = 0; ii < 45; ++ii) {
        float4 xv = *(const float4*)(xrow_ + 4 * ii);   // one ds_read_b128
        float4 wa = *(const float4*)(wA0 + 4 * ii);
        float4 wb = *(const float4*)(wB0 + 4 * ii);
        float4 wc = *(const float4*)(wA1 + 4 * ii);
        float4 wd = *(const float4*)(wB1 + 4 * ii);
        a0 = __builtin_fmaf(wa.x, xv.x, a0); a0 = __builtin_fmaf(wa.y, xv.y, a0);
        a0 = __builtin_fmaf(wa.z, xv.z, a0); a0 = __builtin_fmaf(wa.w, xv.w, a0);
        a1 = __builtin_fmaf(wb.x, xv.x, a1); a1 = __builtin_fmaf(wb.y, xv.y, a1);
        a1 = __builtin_fmaf(wb.z, xv.z, a1); a1 = __builtin_fmaf(wb.w, xv.w, a1);
        a2 = __builtin_fmaf(wc.x, xv.x, a2); a2 = __builtin_fmaf(wc.y, xv.y, a2);
        a2 = __builtin_fmaf(wc.z, xv.z, a2); a2 = __builtin_fmaf(wc.w, xv.w, a2);
        a3 = __builtin_fmaf(wd.x, xv.x, a3); a3 = __builtin_fmaf(wd.y, xv.y, a3);
        a3 = __builtin_fmaf(wd.z, xv.z, a3); a3 = __builtin_fmaf(wd.w, xv.w, a3);
    }

    const float scB = (qb == 0) ? STANH : SSIG;
    float bA0 = bi[gA0] + bh[gA0];
    float bA1 = bi[gA0 + 1] + bh[gA0 + 1];
    float bB0 = bi[gB0] + bh[gB0];
    float bB1 = bi[gB0 + 1] + bh[gB0 + 1];
    float4 o;
    o.x = SSIG * (a0 + bA0);
    o.y = scB  * (a1 + bB0);
    o.z = SSIG * (a2 + bA1);
    o.w = scB  * (a3 + bB1);
    float* dst = xg2 + (((size_t)s * 64 + (b >> 2)) * 64
                        + (b & 3) * 16 + qb * 8 + j0) * 2;
    *(float4*)dst = o;
}

// ======================= Kernel B: 4-wave scan =======================
// r13/r14/r15-verified: A1 layer0, A2 a1p, B layer1, W3 projection;
// 16-slot rings, 130 barriers per wave.
__global__ __launch_bounds__(256, 1) void lstm_scan(
    const float* __restrict__ xg,
    const float* __restrict__ w_hh0,
    const float* __restrict__ w_ih1, const float* __restrict__ w_hh1,
    const float* __restrict__ b_ih1, const float* __restrict__ b_hh1,
    const float* __restrict__ w_reg, const float* __restrict__ b_reg,
    float* __restrict__ out)
{
    __shared__ float ring0[16][64];    // h0(u) at slot u&15
    __shared__ float ring1[16][128];   // a1p(u) (v2) at slot u&15
    __shared__ float ring2[16][64];    // h1(u) at slot u&15

    const int tid = threadIdx.x;
    const int wid = tid >> 6;          // 0=A1, 1=A2, 2=B, 3=proj
    const int lt  = tid & 63;
    const int j   = lt & 7;
    const int b3  = (lt >> 3) & 1;
    const int cc  = lt >> 4;
    const bool b3z = (b3 == 0);
    const int bid = blockIdx.x;        // 0..63

    const int gA = b3 * 8 + j;
    const int gB = (2 + b3) * 8 + j;
    const float sB_ = b3z ? STANH : SSIG;
    const float aB  = b3z ? 2.0f : 1.0f;
    const float bB  = b3z ? -1.0f : 0.0f;

    auto COMBINE2 = [&](float tA, float tB, float& c, float& h) {
        float m  = tA * tB;
        float mr = dppf<ROR8>(m);
        float fa = dppf<ROR8>(tA);
        float ob = dppf<ROR8>(tB);
        float ig = b3z ? m  : mr;
        float f  = b3z ? fa : tA;
        float o  = b3z ? ob : tB;
        c = __builtin_fmaf(f, c, ig);
        float th = __builtin_fmaf(2.0f, __builtin_amdgcn_rcpf(
            1.0f + __builtin_amdgcn_exp2f(STANH * c)), -1.0f);
        h = o * th;
    };

    if (wid == 0) {
        // ----- wave A1: layer-0 recurrence -----
        v2 w0p[8];
        #pragma unroll
        for (int m = 0; m < 8; ++m) {
            int k = j ^ m;
            w0p[m] = v2{SSIG * w_hh0[gA * 8 + k], sB_ * w_hh0[gB * 8 + k]};
        }
        float h0p = 0.f, c0v = 0.f;

        const float* xbase = xg + (size_t)bid * 128 + lt * 2;
        v2 xq[8];
        #pragma unroll
        for (int k = 0; k < 8; ++k) xq[k] = *(const v2*)(xbase + (size_t)k * 8192);

        for (int hh = 0; hh < 64; ++hh) {
            const float* pre = xbase + (size_t)((8 * hh + 8) & 511) * 8192;
            const int sb8 = (hh & 1) * 8;
            #pragma unroll
            for (int k = 0; k < 8; ++k) {
                v2 xc = xq[k];
                xq[k] = *(const v2*)(pre + (size_t)k * 8192);
                float r0[8];
                ROTS8(h0p, r0);
                v2 a0L = __builtin_elementwise_fma(w0p[0], v2{r0[0], r0[0]}, xc);
                v2 a0H = w0p[4] * v2{r0[4], r0[4]};
                #pragma unroll
                for (int m = 1; m < 4; ++m) {
                    a0L = __builtin_elementwise_fma(w0p[m], v2{r0[m], r0[m]}, a0L);
                    a0H = __builtin_elementwise_fma(w0p[m + 4], v2{r0[m + 4], r0[m + 4]}, a0H);
                }
                v2 a0 = a0L + a0H;
                float eA = __builtin_amdgcn_exp2f(a0.x);
                float eB = __builtin_amdgcn_exp2f(a0.y);
                float tA = __builtin_amdgcn_rcpf(1.0f + eA);
                float tB = __builtin_fmaf(aB, __builtin_amdgcn_rcpf(1.0f + eB), bB);
                COMBINE2(tA, tB, c0v, h0p);
                ring0[sb8 + k][lt] = h0p;
                if (k == 3 || k == 7) __syncthreads();   // #1..#128
            }
        }
        __syncthreads();                                  // #129
        __syncthreads();                                  // #130
    } else if (wid == 1) {
        // ----- wave A2: a1p = b1 + Wih1*h0 -----
        v2 wi1p[8];
        #pragma unroll
        for (int m = 0; m < 8; ++m) {
            int k = j ^ m;
            wi1p[m] = v2{SSIG * w_ih1[gA * 8 + k], sB_ * w_ih1[gB * 8 + k]};
        }
        const v2 b1p = v2{SSIG * (b_ih1[gA] + b_hh1[gA]),
                          sB_  * (b_ih1[gB] + b_hh1[gB])};

        __syncthreads();                                  // #1
        for (int p = 1; p <= 128; ++p) {
            const int sb = ((p - 1) & 3) * 4;
            float h0v[4];
            #pragma unroll
            for (int k = 0; k < 4; ++k) h0v[k] = ring0[sb + k][lt];
            #pragma unroll
            for (int k = 0; k < 4; ++k) {
                float r0[8];
                ROTS8(h0v[k], r0);
                v2 a = __builtin_elementwise_fma(wi1p[0], v2{r0[0], r0[0]}, b1p);
                #pragma unroll
                for (int m = 1; m < 8; ++m)
                    a = __builtin_elementwise_fma(wi1p[m], v2{r0[m], r0[m]}, a);
                *(v2*)&ring1[sb + k][lt * 2] = a;
            }
            __syncthreads();                              // #2..#129
        }
        __syncthreads();                                  // #130
    } else if (wid == 2) {
        // ----- wave B: layer-1 recurrence -> ring2 -----
        v2 wh1p[8];
        #pragma unroll
        for (int m = 0; m < 8; ++m) {
            int k = j ^ m;
            wh1p[m] = v2{SSIG * w_hh1[gA * 8 + k], sB_ * w_hh1[gB * 8 + k]};
        }
        float h1p = 0.f, c1v = 0.f;

        auto BODY4 = [&](int p) {
            const int sb = ((p - 2) & 3) * 4;
            v2 a1in[4];
            #pragma unroll
            for (int k = 0; k < 4; ++k) a1in[k] = *(const v2*)&ring1[sb + k][lt * 2];
            #pragma unroll
            for (int k = 0; k < 4; ++k) {
                float r1[8];
                ROTS8(h1p, r1);
                v2 aL = __builtin_elementwise_fma(wh1p[0], v2{r1[0], r1[0]}, a1in[k]);
                v2 aH = wh1p[4] * v2{r1[4], r1[4]};
                #pragma unroll
                for (int m = 1; m < 4; ++m) {
                    aL = __builtin_elementwise_fma(wh1p[m], v2{r1[m], r1[m]}, aL);
                    aH = __builtin_elementwise_fma(wh1p[m + 4], v2{r1[m + 4], r1[m + 4]}, aH);
                }
                v2 a1 = aL + aH;
                float eA = __builtin_amdgcn_exp2f(a1.x);
                float eB = __builtin_amdgcn_exp2f(a1.y);
                float tA = __builtin_amdgcn_rcpf(1.0f + eA);
                float tB = __builtin_fmaf(aB, __builtin_amdgcn_rcpf(1.0f + eB), bB);
                COMBINE2(tA, tB, c1v, h1p);
                ring2[sb + k][lt] = h1p;
            }
        };

        __syncthreads();                                  // #1
        __syncthreads();                                  // #2
        for (int p = 2; p <= 128; ++p) { BODY4(p); __syncthreads(); }  // #3..#129
        BODY4(129);                                       // steps 508..511
        __syncthreads();                                  // #130
    } else {
        // ----- wave W3: projection -----
        float wrl[8];
        #pragma unroll
        for (int m = 0; m < 8; ++m) wrl[m] = w_reg[b3 * 8 + (j ^ m)];
        const float br  = b_reg[b3];
        const bool isl  = (j == 0);
        const int  ooff = (bid * 4 + cc) * 2 + b3;

        auto PBODY = [&](int sb, int wbase) {
            float h1v[4];
            #pragma unroll
            for (int k = 0; k < 4; ++k) h1v[k] = ring2[sb + k][lt];
            #pragma unroll
            for (int k = 0; k < 4; ++k) {
                float r1[8];
                ROTS8(h1v[k], r1);
                float pp = br;
                #pragma unroll
                for (int m = 0; m < 8; ++m) pp = __builtin_fmaf(wrl[m], r1[m], pp);
                if (isl) out[(size_t)(wbase + k) * 512 + ooff] = pp;
            }
        };

        __syncthreads();                                  // #1
        __syncthreads();                                  // #2
        __syncthreads();                                  // #3
        for (int p = 3; p <= 129; ++p) {
            PBODY(((p - 3) & 3) * 4, 4 * (p - 3));
            __syncthreads();                              // #4..#130
        }
        PBODY(12, 508);                                   // steps 508..511
    }
}

extern "C" void kernel_launch(void* const* d_in, const int* in_sizes, int n_in,
                              void* d_out, int out_size, void* d_ws, size_t ws_size,
                              hipStream_t stream) {
    (void)in_sizes; (void)n_in; (void)out_size; (void)ws_size;
    const float* x     = (const float*)d_in[0];
    const float* w_ih0 = (const float*)d_in[1];
    const float* w_hh0 = (const float*)d_in[2];
    const float* b_ih0 = (const float*)d_in[3];
    const float* b_hh0 = (const float*)d_in[4];
    const float* w_ih1 = (const float*)d_in[5];
    const float* w_hh1 = (const float*)d_in[6];
    const float* b_ih1 = (const float*)d_in[7];
    const float* b_hh1 = (const float*)d_in[8];
    const float* w_reg = (const float*)d_in[9];
    const float* b_reg = (const float*)d_in[10];
    float* out = (float*)d_out;
    float* xg2 = (float*)d_ws;   // 512*64*128*4 = 16 MB scratch

    xg_gemm<<<2048, 512, 0, stream>>>(x, w_ih0, b_ih0, b_hh0, xg2);
    lstm_scan<<<64, 256, 0, stream>>>(xg2, w_hh0, w_ih1, w_hh1, b_ih1, b_hh1,
                                      w_reg, b_reg, out);
}